// Round 5
// baseline (1298.944 us; speedup 1.0000x reference)
//
#include <hip/hip_runtime.h>
#include <math.h>

#define Bz 64
#define Sz 200
#define Dz 128
#define NQz 50000
#define NCz 1000
#define MCz 4
#define Kz 10
#define Tz 199            // S-1 scan steps
#define NSz (Bz*Tz)       // 12736 (b,t) slots; 12736/64 = 199 exactly
#define NEz (NQz*MCz)     // 200000 edges

// ---------------- GNN: CSR build + per-concept aggregation ----------------
__global__ void k_count(const int* __restrict__ qt, int* __restrict__ cnt) {
    int e = blockIdx.x*256 + threadIdx.x;
    if (e < NEz) atomicAdd(&cnt[qt[e]], 1);
}

__global__ void k_offs(const int* __restrict__ cnt, int* __restrict__ offs) {
    __shared__ int s[1024];
    int tid = threadIdx.x;
    s[tid] = (tid < NCz) ? cnt[tid] : 0;
    __syncthreads();
    for (int off = 1; off < 1024; off <<= 1) {
        int add = (tid >= off) ? s[tid - off] : 0;
        __syncthreads();
        s[tid] += add;
        __syncthreads();
    }
    if (tid < NCz) offs[tid + 1] = s[tid];
    if (tid == 0) offs[0] = 0;
}

__global__ void k_fill(const int* __restrict__ qt, const int* __restrict__ offs,
                       int* __restrict__ fill, int* __restrict__ edge_q) {
    int e = blockIdx.x*256 + threadIdx.x;
    if (e < NEz) {
        int c = qt[e];
        int pos = atomicAdd(&fill[c], 1);
        edge_q[offs[c] + pos] = e >> 2;     // question id
    }
}

// m2[c] = mean over edges (q->c) of ( emb_q[q] + 0.25*sum_m emb_c[q_table[q][m]] )
__global__ void k_m2(const int* __restrict__ qt, const int* __restrict__ offs,
                     const int* __restrict__ edge_q,
                     const float* __restrict__ emb_q, const float* __restrict__ emb_c,
                     float* __restrict__ m2) {
    int c = blockIdx.x;
    int g = threadIdx.x >> 7;      // 0..3
    int d = threadIdx.x & 127;
    int e0 = offs[c], e1 = offs[c+1];
    float acc = 0.f;
    for (int e = e0 + g; e < e1; e += 4) {
        int q = edge_q[e];
        const int* t4 = qt + q*4;
        int c0 = t4[0], c1 = t4[1], c2 = t4[2], c3 = t4[3];
        acc += emb_q[q*128 + d]
             + 0.25f*(emb_c[c0*128+d] + emb_c[c1*128+d] + emb_c[c2*128+d] + emb_c[c3*128+d]);
    }
    __shared__ float ps[4][128];
    ps[g][d] = acc;
    __syncthreads();
    if (g == 0) {
        float tot = ps[0][d] + ps[1][d] + ps[2][d] + ps[3][d];
        float cn = (float)(e1 - e0);
        m2[c*128 + d] = tot / fmaxf(cn, 1.0f);
    }
}

// ---------------- small 128x128 matmuls (weight folding) ----------------
template<bool TR>
__global__ void k_mm128(const float* __restrict__ X, const float* __restrict__ Y,
                        float* __restrict__ out) {
    int r = blockIdx.x, c = threadIdx.x;
    float acc = 0.f;
    for (int e = 0; e < 128; ++e) acc += X[r*128 + e] * Y[e*128 + c];
    if (TR) out[c*128 + r] = acc;           // store transposed (Mt[d][r] = M[r][d])
    else    out[r*128 + c] = acc;
}

// gr[rt][r] = bih1[r] + sum_e emb_r[rt][e]*Wih1[r][128+e]   (response-part of gi1, bias folded)
__global__ void k_gr(const float* __restrict__ emb_r, const float* __restrict__ Wih1,
                     const float* __restrict__ bih1, float* __restrict__ gr) {
    int rt = threadIdx.x / 384, r = threadIdx.x % 384;   // block 768
    float acc = bih1[r];
    for (int e = 0; e < 128; ++e) acc += emb_r[rt*128 + e] * Wih1[r*256 + 128 + e];
    gr[rt*384 + r] = acc;
}

// Bkq rows 0..127: G = Wq^T Wk;  row 128: wkb = Wk^T bq;  row 129: Ww[0][128:256]
// biaskq: 0..127: Wq^T bk;  128: bq.bk;  129: bw
__global__ void k_bkq(const float* __restrict__ Wq, const float* __restrict__ Wk,
                      const float* __restrict__ bq, const float* __restrict__ bk,
                      const float* __restrict__ Ww, const float* __restrict__ bw,
                      float* __restrict__ Bkq, float* __restrict__ biaskq) {
    int r = blockIdx.x, d = threadIdx.x;
    if (r < 128) {
        float acc = 0.f;
        for (int n = 0; n < 128; ++n) acc += Wq[n*128 + r] * Wk[n*128 + d];
        Bkq[r*128 + d] = acc;
        if (d == 0) {
            float b0 = 0.f;
            for (int n = 0; n < 128; ++n) b0 += Wq[n*128 + r] * bk[n];
            biaskq[r] = b0;
        }
    } else if (r == 128) {
        float acc = 0.f;
        for (int n = 0; n < 128; ++n) acc += bq[n] * Wk[n*128 + d];
        Bkq[128*128 + d] = acc;
        if (d == 0) {
            float c0 = 0.f;
            for (int n = 0; n < 128; ++n) c0 += bq[n] * bk[n];
            biaskq[128] = c0;
        }
    } else {
        Bkq[129*128 + d] = Ww[128 + d];
        if (d == 0) biaskq[129] = bw[0];
    }
}

// ---------------- per-slot GNN question embedding ----------------
// e_q[slot] = mask ? tanh(u @ M^T + bagg) : emb_q[q],  u = emb_q + 0.5*sum(emb_c) + 0.25*sum(m2)
__global__ void k_eq(const float* __restrict__ Mt_g, const float* __restrict__ bagg,
                     const float* __restrict__ emb_q, const float* __restrict__ emb_c,
                     const float* __restrict__ m2, const int* __restrict__ qseq,
                     const int* __restrict__ mseq, const int* __restrict__ qt,
                     float* __restrict__ eq) {
    __shared__ float Mt[128*128];
    __shared__ float ub[2][128];
    int tid = threadIdx.x;
    for (int i = tid; i < 128*128/4; i += 256)
        ((float4*)Mt)[i] = ((const float4*)Mt_g)[i];
    __syncthreads();
    int g = tid >> 7, d = tid & 127;
    for (int it = 0; it < 8; ++it) {
        int slot = blockIdx.x*16 + it*2 + g;            // grid 796 -> slots exactly cover NSz
        int b = slot / Tz, t = slot % Tz;
        int q = qseq[b*Sz + t];
        int msk = mseq[b*Sz + t];
        if (msk) {
            const int* t4 = qt + q*4;
            int c0 = t4[0], c1 = t4[1], c2 = t4[2], c3 = t4[3];
            ub[g][d] = emb_q[q*128 + d]
                     + 0.5f *(emb_c[c0*128+d] + emb_c[c1*128+d] + emb_c[c2*128+d] + emb_c[c3*128+d])
                     + 0.25f*(m2[c0*128+d]  + m2[c1*128+d]  + m2[c2*128+d]  + m2[c3*128+d]);
        }
        __syncthreads();
        if (msk) {
            float acc = bagg[d];
            const float* urow = ub[g];
            for (int e = 0; e < 128; ++e) acc += Mt[e*128 + d] * urow[e];
            eq[slot*128 + d] = tanhf(acc);
        } else {
            eq[slot*128 + d] = emb_q[q*128 + d];
        }
        __syncthreads();
    }
}

// ---------------- generic tiled fp32 GEMM: C[s][n] = A[s][:128] . Bm[n][:128] + epilogue ----
// MODE 0: + bias[n]   (kq path)     MODE 1: + gr[rt(s)][n]  (gi1 path)
template<int MODE>
__global__ void k_gemm(const float* __restrict__ A, const float* __restrict__ Bm,
                       int ldb, int nB, float* __restrict__ C, int ldc,
                       const float* __restrict__ bias, const float* __restrict__ gr,
                       const int* __restrict__ cseq) {
    __shared__ float As[64][33];
    __shared__ float Bs[64][33];
    __shared__ int rtb[64];
    int tx = threadIdx.x, ty = threadIdx.y;
    int tid = ty*16 + tx;
    int m0 = blockIdx.x * 64;
    int n0 = blockIdx.y * 64;
    if (MODE == 1 && tid < 64) {
        int s = m0 + tid;
        int b = s / Tz, t = s % Tz;
        rtb[tid] = cseq[b*Sz + t];
    }
    float acc[4][4];
    #pragma unroll
    for (int i = 0; i < 4; ++i)
        #pragma unroll
        for (int j = 0; j < 4; ++j) acc[i][j] = 0.f;

    for (int kc = 0; kc < 128; kc += 32) {
        #pragma unroll
        for (int l = 0; l < 2; ++l) {
            int v = tid*2 + l;                 // 0..511
            int row = v >> 3, c4 = (v & 7) << 2;
            float4 av = *(const float4*)(A + (size_t)(m0+row)*128 + kc + c4);
            As[row][c4+0] = av.x; As[row][c4+1] = av.y; As[row][c4+2] = av.z; As[row][c4+3] = av.w;
            int nrow = n0 + row;
            float4 bv = make_float4(0.f, 0.f, 0.f, 0.f);
            if (nrow < nB) bv = *(const float4*)(Bm + (size_t)nrow*ldb + kc + c4);
            Bs[row][c4+0] = bv.x; Bs[row][c4+1] = bv.y; Bs[row][c4+2] = bv.z; Bs[row][c4+3] = bv.w;
        }
        __syncthreads();
        #pragma unroll 8
        for (int k = 0; k < 32; ++k) {
            float av[4], bv[4];
            #pragma unroll
            for (int i = 0; i < 4; ++i) av[i] = As[ty*4+i][k];
            #pragma unroll
            for (int j = 0; j < 4; ++j) bv[j] = Bs[tx*4+j][k];
            #pragma unroll
            for (int i = 0; i < 4; ++i)
                #pragma unroll
                for (int j = 0; j < 4; ++j) acc[i][j] += av[i]*bv[j];
        }
        __syncthreads();
    }
    #pragma unroll
    for (int i = 0; i < 4; ++i) {
        int s = m0 + ty*4 + i;
        #pragma unroll
        for (int j = 0; j < 4; ++j) {
            int col = n0 + tx*4 + j;
            if (col < nB) {
                float v = acc[i][j];
                if (MODE == 0) v += bias[col];
                else           v += gr[rtb[ty*4+i]*384 + col];
                C[(size_t)s*ldc + col] = v;
            }
        }
    }
}

// ---------------- sequential GRU scan ----------------
__device__ __forceinline__ float bf_lo(unsigned u){ return __uint_as_float(u << 16); }
__device__ __forceinline__ float bf_hi(unsigned u){ return __uint_as_float(u & 0xffff0000u); }
__device__ __forceinline__ unsigned f2bf(float x){          // RNE round to bf16 (bits in low 16)
    unsigned u = __float_as_uint(x);
    return (u + 0x7fffu + ((u >> 16) & 1u)) >> 16;
}
__device__ __forceinline__ unsigned pk2(float a, float b){
    return f2bf(a) | (f2bf(b) << 16);
}
__device__ __forceinline__ float sigm(float x){ return 1.f/(1.f + __expf(-x)); }

#if __has_builtin(__builtin_amdgcn_fdot2_f32_bf16)
typedef __attribute__((ext_vector_type(2))) short short2v;
__device__ __forceinline__ float bdot2(unsigned w, unsigned h, float acc) {
    return __builtin_amdgcn_fdot2_f32_bf16(__builtin_bit_cast(short2v, w),
                                           __builtin_bit_cast(short2v, h), acc, false);
}
#else
__device__ __forceinline__ float bdot2(unsigned w, unsigned h, float acc) {
    return acc + bf_lo(w)*bf_lo(h) + bf_hi(w)*bf_hi(h);
}
#endif

// One block per batch row, 768 threads (12 waves = exactly 3 waves/EU with 1 block/CU).
// Phase A: tid<384 holds Whh1 row tid (64 packed-bf16 regs) -> ghA; tid>=384 holds Whh2 row.
// Phase B: Wih2 row r split in half across tid=r and tid=384+r (32 regs each).
// Weight regs/thread = 96; total ~120 VGPR.
// amdgpu_waves_per_eu(3,3): pin occupancy target at 3 waves/EU -> 168-VGPR budget; the
// backend's heuristic may NOT shrink to 6 waves/EU (which caused the 84-VGPR spill in r4).
__global__ void __launch_bounds__(768)
__attribute__((amdgpu_waves_per_eu(3, 3)))
k_scan(const float* __restrict__ gi1,
       const float* __restrict__ Whh1, const float* __restrict__ bhh1,
       const float* __restrict__ Wih2, const float* __restrict__ bih2,
       const float* __restrict__ Whh2, const float* __restrict__ bhh2,
       float* __restrict__ stateh) {
    int b = blockIdx.x, tid = threadIdx.x;
    int lo = (tid < 384);
    int r384 = lo ? tid : tid - 384;

    // phase-A weight row (Whh1 or Whh2), packed bf16
    unsigned wAC[64];
    {
        const float4* w4 = (const float4*)((lo ? Whh1 : Whh2) + (size_t)r384*128);
        #pragma unroll
        for (int k = 0; k < 32; ++k) {
            float4 v = w4[k];
            wAC[2*k] = pk2(v.x, v.y); wAC[2*k+1] = pk2(v.z, v.w);
        }
    }
    // phase-B half row of Wih2
    unsigned wBh[32];
    {
        const float4* w4 = (const float4*)(Wih2 + (size_t)r384*128 + (lo ? 0 : 64));
        #pragma unroll
        for (int k = 0; k < 16; ++k) {
            float4 v = w4[k];
            wBh[2*k] = pk2(v.x, v.y); wBh[2*k+1] = pk2(v.z, v.w);
        }
    }
    float bAC = lo ? bhh1[r384] : bhh2[r384];
    float bB  = lo ? bih2[r384] : 0.f;

    __shared__ unsigned h1b[64], h2b[64];      // h packed bf16
    __shared__ float ghA[384], ghC[384], giB2[768];
    if (tid < 64) { h1b[tid] = 0u; h2b[tid] = 0u; }

    float g[6];
    #pragma unroll
    for (int i = 0; i < 6; ++i) g[i] = 0.f;
    if (tid < 64) {
        const float2* gp = (const float2*)(gi1 + (size_t)(b*Tz)*384);
        float2 x0 = gp[tid], x1 = gp[tid+64], x2 = gp[tid+128];
        g[0]=x0.x; g[1]=x0.y; g[2]=x1.x; g[3]=x1.y; g[4]=x2.x; g[5]=x2.y;
    }
    __syncthreads();

    const uint2* hA = lo ? (const uint2*)h1b : (const uint2*)h2b;
    const uint2* hB = (const uint2*)(h1b + (lo ? 0 : 32));

    for (int t = 0; t < Tz; ++t) {
        float n[6];
        #pragma unroll
        for (int i = 0; i < 6; ++i) n[i] = 0.f;
        if (tid < 64 && t + 1 < Tz) {                 // prefetch next step's input gates
            const float2* gp = (const float2*)(gi1 + (size_t)(b*Tz + t + 1)*384);
            float2 x0 = gp[tid], x1 = gp[tid+64], x2 = gp[tid+128];
            n[0]=x0.x; n[1]=x0.y; n[2]=x1.x; n[3]=x1.y; n[4]=x2.x; n[5]=x2.y;
        }
        // phase A: ghA = Whh1@h1 + bhh1 (tid<384); ghC = Whh2@h2 + bhh2 (tid>=384)
        {
            float a0 = 0.f, a1 = 0.f;
            #pragma unroll
            for (int k = 0; k < 32; ++k) {
                uint2 hp = hA[k];                     // uniform LDS broadcast
                a0 = bdot2(wAC[2*k],   hp.x, a0);
                a1 = bdot2(wAC[2*k+1], hp.y, a1);
            }
            if (lo) ghA[r384] = bAC + a0 + a1;
            else    ghC[r384] = bAC + a0 + a1;
        }
        __syncthreads();
        if (tid < 64) {   // gate 1: update h1 (2 units per thread)
            unsigned hp = h1b[tid];
            float r0 = sigm(g[0] + ghA[2*tid]);
            float r1 = sigm(g[1] + ghA[2*tid+1]);
            float z0 = sigm(g[2] + ghA[2*tid+128]);
            float z1 = sigm(g[3] + ghA[2*tid+129]);
            float q0 = tanhf(g[4] + r0*ghA[2*tid+256]);
            float q1 = tanhf(g[5] + r1*ghA[2*tid+257]);
            float h0 = (1.f - z0)*q0 + z0*bf_lo(hp);
            float h1v = (1.f - z1)*q1 + z1*bf_hi(hp);
            h1b[tid] = pk2(h0, h1v);
        }
        __syncthreads();
        // phase B: giB = Wih2@h1' + bih2 (half rows; halves summed at gate 2)
        {
            float d0 = 0.f, d1 = 0.f;
            #pragma unroll
            for (int k = 0; k < 16; ++k) {
                uint2 hp = hB[k];
                d0 = bdot2(wBh[2*k],   hp.x, d0);
                d1 = bdot2(wBh[2*k+1], hp.y, d1);
            }
            giB2[tid] = bB + d0 + d1;
        }
        __syncthreads();
        if (tid < 64) {   // gate 2: update h2, store fp32 state
            unsigned hp = h2b[tid];
            float i0 = giB2[2*tid]     + giB2[384+2*tid];
            float i1 = giB2[2*tid+1]   + giB2[384+2*tid+1];
            float i2 = giB2[2*tid+128] + giB2[384+2*tid+128];
            float i3 = giB2[2*tid+129] + giB2[384+2*tid+129];
            float i4 = giB2[2*tid+256] + giB2[384+2*tid+256];
            float i5 = giB2[2*tid+257] + giB2[384+2*tid+257];
            float r0 = sigm(i0 + ghC[2*tid]);
            float r1 = sigm(i1 + ghC[2*tid+1]);
            float z0 = sigm(i2 + ghC[2*tid+128]);
            float z1 = sigm(i3 + ghC[2*tid+129]);
            float q0 = tanhf(i4 + r0*ghC[2*tid+256]);
            float q1 = tanhf(i5 + r1*ghC[2*tid+257]);
            float h0 = (1.f - z0)*q0 + z0*bf_lo(hp);
            float h1v = (1.f - z1)*q1 + z1*bf_hi(hp);
            h2b[tid] = pk2(h0, h1v);
            ((float2*)(stateh + (size_t)(b*Tz + t)*128))[tid] = make_float2(h0, h1v);
        }
        #pragma unroll
        for (int i = 0; i < 6; ++i) g[i] = n[i];
        __syncthreads();
    }
}

// ---------------- attention + top-k + output, one wave per (b,t) ----------------
__global__ void k_attn(const float* __restrict__ kqb, const int* __restrict__ qseq,
                       const int* __restrict__ qt, const float* __restrict__ emb_q,
                       const float* __restrict__ emb_c, const float* __restrict__ Ww,
                       float* __restrict__ out) {
    int t = blockIdx.x, b = blockIdx.y;
    int lane = threadIdx.x;           // block = 64 = 1 wave
    __shared__ float qc[5][128];
    __shared__ float gq[5];
    int qn = qseq[b*Sz + t + 1];
    for (int idx = lane; idx < 5*128; idx += 64) {
        int i = idx >> 7, d = idx & 127;
        const float* src = (i == 0) ? (emb_q + (size_t)qn*128)
                                    : (emb_c + (size_t)qt[qn*4 + (i-1)]*128);
        qc[i][d] = src[d];
    }
    __syncthreads();
    if (lane < 5) {
        float acc = 0.f;
        for (int d = 0; d < 128; ++d) acc += qc[lane][d]*Ww[d];
        gq[lane] = acc;
    }
    __syncthreads();

    const float NEG = -3.402823466e38f;
    float sv[10]; int si[10];
    #pragma unroll
    for (int k = 0; k < 10; ++k) { sv[k] = NEG; si[k] = 0x7FFFFFFF; }

    for (int j = lane; j <= t; j += 64) {
        const float* krow = kqb + (size_t)(b*Tz + j)*132;
        const float4* kr4 = (const float4*)krow;
        float a0=0.f, a1=0.f, a2=0.f, a3=0.f, a4=0.f;
        #pragma unroll 4
        for (int c = 0; c < 32; ++c) {
            float4 kv = kr4[c];
            float4 q0 = ((const float4*)qc[0])[c];
            float4 q1 = ((const float4*)qc[1])[c];
            float4 q2 = ((const float4*)qc[2])[c];
            float4 q3 = ((const float4*)qc[3])[c];
            float4 q4 = ((const float4*)qc[4])[c];
            a0 += q0.x*kv.x + q0.y*kv.y + q0.z*kv.z + q0.w*kv.w;
            a1 += q1.x*kv.x + q1.y*kv.y + q1.z*kv.z + q1.w*kv.w;
            a2 += q2.x*kv.x + q2.y*kv.y + q2.z*kv.z + q2.w*kv.w;
            a3 += q3.x*kv.x + q3.y*kv.y + q3.z*kv.z + q3.w*kv.w;
            a4 += q4.x*kv.x + q4.y*kv.y + q4.z*kv.z + q4.w*kv.w;
        }
        float kbj = krow[128];
        float scs[5] = {a0+kbj, a1+kbj, a2+kbj, a3+kbj, a4+kbj};
        #pragma unroll
        for (int i = 0; i < 5; ++i) {
            float cv = scs[i]; int ci = i*Sz + j;        // flat idx = i*S + j (ref order)
            #pragma unroll
            for (int k = 0; k < 10; ++k) {
                bool bet = (cv > sv[k]) || (cv == sv[k] && ci < si[k]);
                float tvv = sv[k]; int tii = si[k];
                if (bet) { sv[k] = cv; si[k] = ci; cv = tvv; ci = tii; }
            }
        }
    }

    // 10 rounds of global max (desc value, tie -> lower index), matching lax.top_k order
    float vmax = 0.f, myv = 0.f; int myidx = 0x7FFFFFFF;
    #pragma unroll
    for (int rnd = 0; rnd < 10; ++rnd) {
        float v = sv[0]; int idx = si[0];
        #pragma unroll
        for (int off = 32; off >= 1; off >>= 1) {
            float ov = __shfl_xor(v, off);
            int   oi = __shfl_xor(idx, off);
            if (ov > v || (ov == v && oi < idx)) { v = ov; idx = oi; }
        }
        if (rnd == 0) vmax = v;
        if (lane == rnd) { myv = v; myidx = idx; }
        if (si[0] == idx) {   // owner pops its head
            #pragma unroll
            for (int k = 0; k < 9; ++k) { sv[k] = sv[k+1]; si[k] = si[k+1]; }
            sv[9] = NEG; si[9] = 0x7FFFFFFF;
        }
    }

    float num = 0.f, den = 0.f;
    if (lane < 10 && myidx != 0x7FFFFFFF) {
        float a = expf(myv - vmax);
        int ik = myidx / Sz, jk = myidx % Sz;
        float gsj = kqb[(size_t)(b*Tz + jk)*132 + 129];       // Ww-state dot + bw
        float f = 1.f/(1.f + expf(-(gq[ik] + gsj)));
        num = a*f; den = a;
    }
    #pragma unroll
    for (int off = 32; off >= 1; off >>= 1) {
        num += __shfl_xor(num, off);
        den += __shfl_xor(den, off);
    }
    if (lane == 0) out[b*Sz + t + 1] = num/den;
}

// ---------------- host ----------------
static inline size_t alup(size_t x) { return (x + 255) & ~(size_t)255; }

extern "C" void kernel_launch(void* const* d_in, const int* in_sizes, int n_in,
                              void* d_out, int out_size, void* d_ws, size_t ws_size,
                              hipStream_t stream) {
    (void)in_sizes; (void)n_in; (void)ws_size;
    const float* emb_q = (const float*)d_in[0];
    const float* emb_c = (const float*)d_in[1];
    const float* emb_r = (const float*)d_in[2];
    const float* Wih1  = (const float*)d_in[3];
    const float* Whh1  = (const float*)d_in[4];
    const float* bih1  = (const float*)d_in[5];
    const float* bhh1  = (const float*)d_in[6];
    const float* Wih2  = (const float*)d_in[7];
    const float* Whh2  = (const float*)d_in[8];
    const float* bih2  = (const float*)d_in[9];
    const float* bhh2  = (const float*)d_in[10];
    const float* Wg1   = (const float*)d_in[11];
    const float* Wg2   = (const float*)d_in[12];
    const float* Wg3   = (const float*)d_in[13];
    const float* Wagg  = (const float*)d_in[14];
    const float* bagg  = (const float*)d_in[15];
    const float* Wq    = (const float*)d_in[16];
    const float* bq    = (const float*)d_in[17];
    const float* Wk    = (const float*)d_in[18];
    const float* bk    = (const float*)d_in[19];
    const float* Ww    = (const float*)d_in[20];
    const float* bw    = (const float*)d_in[21];
    const int* qseq    = (const int*)d_in[22];
    const int* cseq    = (const int*)d_in[23];
    const int* mseq    = (const int*)d_in[24];
    const int* qtab    = (const int*)d_in[25];
    float* out = (float*)d_out;

    char* p = (char*)d_ws;
    auto alloc = [&](size_t bytes) { char* r = p; p += alup(bytes); return r; };
    int*   cnt    = (int*)  alloc(4096);
    int*   fill   = (int*)  alloc(4096);               // contiguous with cnt
    int*   offs   = (int*)  alloc(1001*4);
    int*   edge_q = (int*)  alloc((size_t)NEz*4);
    float* m2     = (float*)alloc((size_t)NCz*128*4);
    float* T1     = (float*)alloc(128*128*4);
    float* T2     = (float*)alloc(128*128*4);
    float* Mt     = (float*)alloc(128*128*4);
    float* gr     = (float*)alloc(2*384*4);
    float* Bkq    = (float*)alloc(132*128*4);
    float* biaskq = (float*)alloc(132*4);
    float* eq     = (float*)alloc((size_t)NSz*128*4);
    float* gi1    = (float*)alloc((size_t)NSz*384*4);
    float* stateh = (float*)alloc((size_t)NSz*128*4);
    float* kqb    = (float*)alloc((size_t)NSz*132*4);

    hipMemsetAsync(cnt, 0, 8192, stream);                       // cnt + fill
    hipMemsetAsync(d_out, 0, (size_t)out_size*4, stream);       // y[:,0] = 0

    k_count<<<(NEz+255)/256, 256, 0, stream>>>(qtab, cnt);
    k_offs <<<1, 1024, 0, stream>>>(cnt, offs);
    k_fill <<<(NEz+255)/256, 256, 0, stream>>>(qtab, offs, fill, edge_q);
    k_m2   <<<NCz, 512, 0, stream>>>(qtab, offs, edge_q, emb_q, emb_c, m2);

    k_mm128<false><<<128, 128, 0, stream>>>(Wg2, Wg1, T1);      // T1 = Wg2*Wg1
    k_mm128<false><<<128, 128, 0, stream>>>(Wg3, T1, T2);       // T2 = Wg3*T1
    k_mm128<true> <<<128, 128, 0, stream>>>(Wagg, T2, Mt);      // Mt = (Wagg*T2)^T
    k_gr  <<<1, 768, 0, stream>>>(emb_r, Wih1, bih1, gr);
    k_bkq <<<130, 128, 0, stream>>>(Wq, Wk, bq, bk, Ww, bw, Bkq, biaskq);

    k_eq  <<<NSz/16, 256, 0, stream>>>(Mt, bagg, emb_q, emb_c, m2, qseq, mseq, qtab, eq);

    k_gemm<1><<<dim3(NSz/64, 6), dim3(16,16), 0, stream>>>(eq, Wih1, 256, 384,
                                                           gi1, 384, nullptr, gr, cseq);
    k_scan<<<Bz, 768, 0, stream>>>(gi1, Whh1, bhh1, Wih2, bih2, Whh2, bhh2, stateh);
    k_gemm<0><<<dim3(NSz/64, 3), dim3(16,16), 0, stream>>>(stateh, Bkq, 128, 132,
                                                           kqb, 132, biaskq, nullptr, nullptr);
    k_attn<<<dim3(Tz, Bz), 64, 0, stream>>>(kqb, qseq, qtab, emb_q, emb_c, Ww, out);
}

// Round 6
// 766.203 us; speedup vs baseline: 1.6953x; 1.6953x over previous
//
#include <hip/hip_runtime.h>
#include <math.h>

#define Bz 64
#define Sz 200
#define Dz 128
#define NQz 50000
#define NCz 1000
#define MCz 4
#define Kz 10
#define Tz 199            // S-1 scan steps
#define NSz (Bz*Tz)       // 12736 (b,t) slots; 12736/64 = 199 exactly
#define NEz (NQz*MCz)     // 200000 edges

// ---------------- GNN: CSR build + per-concept aggregation ----------------
__global__ void k_count(const int* __restrict__ qt, int* __restrict__ cnt) {
    int e = blockIdx.x*256 + threadIdx.x;
    if (e < NEz) atomicAdd(&cnt[qt[e]], 1);
}

__global__ void k_offs(const int* __restrict__ cnt, int* __restrict__ offs) {
    __shared__ int s[1024];
    int tid = threadIdx.x;
    s[tid] = (tid < NCz) ? cnt[tid] : 0;
    __syncthreads();
    for (int off = 1; off < 1024; off <<= 1) {
        int add = (tid >= off) ? s[tid - off] : 0;
        __syncthreads();
        s[tid] += add;
        __syncthreads();
    }
    if (tid < NCz) offs[tid + 1] = s[tid];
    if (tid == 0) offs[0] = 0;
}

__global__ void k_fill(const int* __restrict__ qt, const int* __restrict__ offs,
                       int* __restrict__ fill, int* __restrict__ edge_q) {
    int e = blockIdx.x*256 + threadIdx.x;
    if (e < NEz) {
        int c = qt[e];
        int pos = atomicAdd(&fill[c], 1);
        edge_q[offs[c] + pos] = e >> 2;     // question id
    }
}

// m2[c] = mean over edges (q->c) of ( emb_q[q] + 0.25*sum_m emb_c[q_table[q][m]] )
__global__ void k_m2(const int* __restrict__ qt, const int* __restrict__ offs,
                     const int* __restrict__ edge_q,
                     const float* __restrict__ emb_q, const float* __restrict__ emb_c,
                     float* __restrict__ m2) {
    int c = blockIdx.x;
    int g = threadIdx.x >> 7;      // 0..3
    int d = threadIdx.x & 127;
    int e0 = offs[c], e1 = offs[c+1];
    float acc = 0.f;
    for (int e = e0 + g; e < e1; e += 4) {
        int q = edge_q[e];
        const int* t4 = qt + q*4;
        int c0 = t4[0], c1 = t4[1], c2 = t4[2], c3 = t4[3];
        acc += emb_q[q*128 + d]
             + 0.25f*(emb_c[c0*128+d] + emb_c[c1*128+d] + emb_c[c2*128+d] + emb_c[c3*128+d]);
    }
    __shared__ float ps[4][128];
    ps[g][d] = acc;
    __syncthreads();
    if (g == 0) {
        float tot = ps[0][d] + ps[1][d] + ps[2][d] + ps[3][d];
        float cn = (float)(e1 - e0);
        m2[c*128 + d] = tot / fmaxf(cn, 1.0f);
    }
}

// ---------------- small 128x128 matmuls (weight folding) ----------------
template<bool TR>
__global__ void k_mm128(const float* __restrict__ X, const float* __restrict__ Y,
                        float* __restrict__ out) {
    int r = blockIdx.x, c = threadIdx.x;
    float acc = 0.f;
    for (int e = 0; e < 128; ++e) acc += X[r*128 + e] * Y[e*128 + c];
    if (TR) out[c*128 + r] = acc;           // store transposed (Mt[d][r] = M[r][d])
    else    out[r*128 + c] = acc;
}

// gr[rt][r] = bih1[r] + sum_e emb_r[rt][e]*Wih1[r][128+e]   (response-part of gi1, bias folded)
__global__ void k_gr(const float* __restrict__ emb_r, const float* __restrict__ Wih1,
                     const float* __restrict__ bih1, float* __restrict__ gr) {
    int rt = threadIdx.x / 384, r = threadIdx.x % 384;   // block 768
    float acc = bih1[r];
    for (int e = 0; e < 128; ++e) acc += emb_r[rt*128 + e] * Wih1[r*256 + 128 + e];
    gr[rt*384 + r] = acc;
}

// Bkq rows 0..127: G = Wq^T Wk;  row 128: wkb = Wk^T bq;  row 129: Ww[0][128:256]
// biaskq: 0..127: Wq^T bk;  128: bq.bk;  129: bw
__global__ void k_bkq(const float* __restrict__ Wq, const float* __restrict__ Wk,
                      const float* __restrict__ bq, const float* __restrict__ bk,
                      const float* __restrict__ Ww, const float* __restrict__ bw,
                      float* __restrict__ Bkq, float* __restrict__ biaskq) {
    int r = blockIdx.x, d = threadIdx.x;
    if (r < 128) {
        float acc = 0.f;
        for (int n = 0; n < 128; ++n) acc += Wq[n*128 + r] * Wk[n*128 + d];
        Bkq[r*128 + d] = acc;
        if (d == 0) {
            float b0 = 0.f;
            for (int n = 0; n < 128; ++n) b0 += Wq[n*128 + r] * bk[n];
            biaskq[r] = b0;
        }
    } else if (r == 128) {
        float acc = 0.f;
        for (int n = 0; n < 128; ++n) acc += bq[n] * Wk[n*128 + d];
        Bkq[128*128 + d] = acc;
        if (d == 0) {
            float c0 = 0.f;
            for (int n = 0; n < 128; ++n) c0 += bq[n] * bk[n];
            biaskq[128] = c0;
        }
    } else {
        Bkq[129*128 + d] = Ww[128 + d];
        if (d == 0) biaskq[129] = bw[0];
    }
}

// ---------------- per-slot GNN question embedding ----------------
// e_q[slot] = mask ? tanh(u @ M^T + bagg) : emb_q[q],  u = emb_q + 0.5*sum(emb_c) + 0.25*sum(m2)
__global__ void k_eq(const float* __restrict__ Mt_g, const float* __restrict__ bagg,
                     const float* __restrict__ emb_q, const float* __restrict__ emb_c,
                     const float* __restrict__ m2, const int* __restrict__ qseq,
                     const int* __restrict__ mseq, const int* __restrict__ qt,
                     float* __restrict__ eq) {
    __shared__ float Mt[128*128];
    __shared__ float ub[2][128];
    int tid = threadIdx.x;
    for (int i = tid; i < 128*128/4; i += 256)
        ((float4*)Mt)[i] = ((const float4*)Mt_g)[i];
    __syncthreads();
    int g = tid >> 7, d = tid & 127;
    for (int it = 0; it < 8; ++it) {
        int slot = blockIdx.x*16 + it*2 + g;            // grid 796 -> slots exactly cover NSz
        int b = slot / Tz, t = slot % Tz;
        int q = qseq[b*Sz + t];
        int msk = mseq[b*Sz + t];
        if (msk) {
            const int* t4 = qt + q*4;
            int c0 = t4[0], c1 = t4[1], c2 = t4[2], c3 = t4[3];
            ub[g][d] = emb_q[q*128 + d]
                     + 0.5f *(emb_c[c0*128+d] + emb_c[c1*128+d] + emb_c[c2*128+d] + emb_c[c3*128+d])
                     + 0.25f*(m2[c0*128+d]  + m2[c1*128+d]  + m2[c2*128+d]  + m2[c3*128+d]);
        }
        __syncthreads();
        if (msk) {
            float acc = bagg[d];
            const float* urow = ub[g];
            for (int e = 0; e < 128; ++e) acc += Mt[e*128 + d] * urow[e];
            eq[slot*128 + d] = tanhf(acc);
        } else {
            eq[slot*128 + d] = emb_q[q*128 + d];
        }
        __syncthreads();
    }
}

// ---------------- generic tiled fp32 GEMM: C[s][n] = A[s][:128] . Bm[n][:128] + epilogue ----
// MODE 0: + bias[n]   (kq / gi2 paths)     MODE 1: + gr[rt(s)][n]  (gi1 path)
template<int MODE>
__global__ void k_gemm(const float* __restrict__ A, const float* __restrict__ Bm,
                       int ldb, int nB, float* __restrict__ C, int ldc,
                       const float* __restrict__ bias, const float* __restrict__ gr,
                       const int* __restrict__ cseq) {
    __shared__ float As[64][33];
    __shared__ float Bs[64][33];
    __shared__ int rtb[64];
    int tx = threadIdx.x, ty = threadIdx.y;
    int tid = ty*16 + tx;
    int m0 = blockIdx.x * 64;
    int n0 = blockIdx.y * 64;
    if (MODE == 1 && tid < 64) {
        int s = m0 + tid;
        int b = s / Tz, t = s % Tz;
        rtb[tid] = cseq[b*Sz + t];
    }
    float acc[4][4];
    #pragma unroll
    for (int i = 0; i < 4; ++i)
        #pragma unroll
        for (int j = 0; j < 4; ++j) acc[i][j] = 0.f;

    for (int kc = 0; kc < 128; kc += 32) {
        #pragma unroll
        for (int l = 0; l < 2; ++l) {
            int v = tid*2 + l;                 // 0..511
            int row = v >> 3, c4 = (v & 7) << 2;
            float4 av = *(const float4*)(A + (size_t)(m0+row)*128 + kc + c4);
            As[row][c4+0] = av.x; As[row][c4+1] = av.y; As[row][c4+2] = av.z; As[row][c4+3] = av.w;
            int nrow = n0 + row;
            float4 bv = make_float4(0.f, 0.f, 0.f, 0.f);
            if (nrow < nB) bv = *(const float4*)(Bm + (size_t)nrow*ldb + kc + c4);
            Bs[row][c4+0] = bv.x; Bs[row][c4+1] = bv.y; Bs[row][c4+2] = bv.z; Bs[row][c4+3] = bv.w;
        }
        __syncthreads();
        #pragma unroll 8
        for (int k = 0; k < 32; ++k) {
            float av[4], bv[4];
            #pragma unroll
            for (int i = 0; i < 4; ++i) av[i] = As[ty*4+i][k];
            #pragma unroll
            for (int j = 0; j < 4; ++j) bv[j] = Bs[tx*4+j][k];
            #pragma unroll
            for (int i = 0; i < 4; ++i)
                #pragma unroll
                for (int j = 0; j < 4; ++j) acc[i][j] += av[i]*bv[j];
        }
        __syncthreads();
    }
    #pragma unroll
    for (int i = 0; i < 4; ++i) {
        int s = m0 + ty*4 + i;
        #pragma unroll
        for (int j = 0; j < 4; ++j) {
            int col = n0 + tx*4 + j;
            if (col < nB) {
                float v = acc[i][j];
                if (MODE == 0) v += bias[col];
                else           v += gr[rtb[ty*4+i]*384 + col];
                C[(size_t)s*ldc + col] = v;
            }
        }
    }
}

// ---------------- sequential GRU scan helpers ----------------
__device__ __forceinline__ float bf_lo(unsigned u){ return __uint_as_float(u << 16); }
__device__ __forceinline__ float bf_hi(unsigned u){ return __uint_as_float(u & 0xffff0000u); }
__device__ __forceinline__ unsigned f2bf(float x){          // RNE round to bf16 (bits in low 16)
    unsigned u = __float_as_uint(x);
    return (u + 0x7fffu + ((u >> 16) & 1u)) >> 16;
}
__device__ __forceinline__ unsigned pk2(float a, float b){
    return f2bf(a) | (f2bf(b) << 16);
}
__device__ __forceinline__ float sigm(float x){ return 1.f/(1.f + __expf(-x)); }

#if __has_builtin(__builtin_amdgcn_fdot2_f32_bf16)
typedef __attribute__((ext_vector_type(2))) short short2v;
__device__ __forceinline__ float bdot2(unsigned w, unsigned h, float acc) {
    return __builtin_amdgcn_fdot2_f32_bf16(__builtin_bit_cast(short2v, w),
                                           __builtin_bit_cast(short2v, h), acc, false);
}
#else
__device__ __forceinline__ float bdot2(unsigned w, unsigned h, float acc) {
    return acc + bf_lo(w)*bf_lo(h) + bf_hi(w)*bf_hi(h);
}
#endif

// ---------------- single-layer GRU scan: gh = Whh@h + bhh; gates from precomputed gi ----
// One block per batch row, 768 threads. Thread (hf, r): half-row Whh[r][hf*64..hf*64+63]
// as 32 packed-bf16 VGPRs (+ ~25 working regs = ~60 total -> fits ANY occupancy cap,
// no spill). Row halves summed via LDS part[]. Layer split: h1 scan -> gi2 GEMM -> h2 scan
// (layer-2 input gates are a batch GEMM once h1 is known; no need for 3 matrices resident).
__global__ void __launch_bounds__(768)
k_scan(const float* __restrict__ gi, const float* __restrict__ Whh,
       const float* __restrict__ bhh, float* __restrict__ hout) {
    int b = blockIdx.x, tid = threadIdx.x;
    int hf = (tid >= 384) ? 1 : 0;
    int r  = tid - hf*384;

    unsigned w[32];
    {
        const float4* w4 = (const float4*)(Whh + (size_t)r*128 + hf*64);
        #pragma unroll
        for (int k = 0; k < 16; ++k) {
            float4 v = w4[k];
            w[2*k] = pk2(v.x, v.y); w[2*k+1] = pk2(v.z, v.w);
        }
    }
    float bb = hf ? 0.f : bhh[r];

    __shared__ unsigned hb[64];        // h packed bf16 (128 units)
    __shared__ float part[768];        // per-(row,half) partial dots
    if (tid < 64) hb[tid] = 0u;

    float g[6];
    #pragma unroll
    for (int i = 0; i < 6; ++i) g[i] = 0.f;
    if (tid < 64) {
        const float2* gp = (const float2*)(gi + (size_t)(b*Tz)*384);
        float2 x0 = gp[tid], x1 = gp[tid+64], x2 = gp[tid+128];
        g[0]=x0.x; g[1]=x0.y; g[2]=x1.x; g[3]=x1.y; g[4]=x2.x; g[5]=x2.y;
    }
    __syncthreads();

    const uint2* hv = (const uint2*)hb + hf*16;

    for (int t = 0; t < Tz; ++t) {
        float n[6];
        #pragma unroll
        for (int i = 0; i < 6; ++i) n[i] = 0.f;
        if (tid < 64 && t + 1 < Tz) {                 // prefetch next step's input gates
            const float2* gp = (const float2*)(gi + (size_t)(b*Tz + t + 1)*384);
            float2 x0 = gp[tid], x1 = gp[tid+64], x2 = gp[tid+128];
            n[0]=x0.x; n[1]=x0.y; n[2]=x1.x; n[3]=x1.y; n[4]=x2.x; n[5]=x2.y;
        }
        // half-row dot: 16 uniform ds_read_b64 + 32 dot2
        float a0 = 0.f, a1 = 0.f;
        #pragma unroll
        for (int k = 0; k < 16; ++k) {
            uint2 hp = hv[k];
            a0 = bdot2(w[2*k],   hp.x, a0);
            a1 = bdot2(w[2*k+1], hp.y, a1);
        }
        part[tid] = bb + a0 + a1;
        __syncthreads();
        if (tid < 64) {   // gate phase: 2 units per thread
            int u = 2*tid;
            float gr0 = part[u]     + part[u+384];
            float gr1 = part[u+1]   + part[u+385];
            float gz0 = part[u+128] + part[u+512];
            float gz1 = part[u+129] + part[u+513];
            float gn0 = part[u+256] + part[u+640];
            float gn1 = part[u+257] + part[u+641];
            unsigned hp = hb[tid];
            float r0 = sigm(g[0] + gr0), r1 = sigm(g[1] + gr1);
            float z0 = sigm(g[2] + gz0), z1 = sigm(g[3] + gz1);
            float q0 = tanhf(g[4] + r0*gn0), q1 = tanhf(g[5] + r1*gn1);
            float h0  = (1.f - z0)*q0 + z0*bf_lo(hp);
            float h1v = (1.f - z1)*q1 + z1*bf_hi(hp);
            hb[tid] = pk2(h0, h1v);
            ((float2*)(hout + (size_t)(b*Tz + t)*128))[tid] = make_float2(h0, h1v);
        }
        #pragma unroll
        for (int i = 0; i < 6; ++i) g[i] = n[i];
        __syncthreads();
    }
}

// ---------------- attention + top-k + output, one wave per (b,t) ----------------
__global__ void k_attn(const float* __restrict__ kqb, const int* __restrict__ qseq,
                       const int* __restrict__ qt, const float* __restrict__ emb_q,
                       const float* __restrict__ emb_c, const float* __restrict__ Ww,
                       float* __restrict__ out) {
    int t = blockIdx.x, b = blockIdx.y;
    int lane = threadIdx.x;           // block = 64 = 1 wave
    __shared__ float qc[5][128];
    __shared__ float gq[5];
    int qn = qseq[b*Sz + t + 1];
    for (int idx = lane; idx < 5*128; idx += 64) {
        int i = idx >> 7, d = idx & 127;
        const float* src = (i == 0) ? (emb_q + (size_t)qn*128)
                                    : (emb_c + (size_t)qt[qn*4 + (i-1)]*128);
        qc[i][d] = src[d];
    }
    __syncthreads();
    if (lane < 5) {
        float acc = 0.f;
        for (int d = 0; d < 128; ++d) acc += qc[lane][d]*Ww[d];
        gq[lane] = acc;
    }
    __syncthreads();

    const float NEG = -3.402823466e38f;
    float sv[10]; int si[10];
    #pragma unroll
    for (int k = 0; k < 10; ++k) { sv[k] = NEG; si[k] = 0x7FFFFFFF; }

    for (int j = lane; j <= t; j += 64) {
        const float* krow = kqb + (size_t)(b*Tz + j)*132;
        const float4* kr4 = (const float4*)krow;
        float a0=0.f, a1=0.f, a2=0.f, a3=0.f, a4=0.f;
        #pragma unroll 4
        for (int c = 0; c < 32; ++c) {
            float4 kv = kr4[c];
            float4 q0 = ((const float4*)qc[0])[c];
            float4 q1 = ((const float4*)qc[1])[c];
            float4 q2 = ((const float4*)qc[2])[c];
            float4 q3 = ((const float4*)qc[3])[c];
            float4 q4 = ((const float4*)qc[4])[c];
            a0 += q0.x*kv.x + q0.y*kv.y + q0.z*kv.z + q0.w*kv.w;
            a1 += q1.x*kv.x + q1.y*kv.y + q1.z*kv.z + q1.w*kv.w;
            a2 += q2.x*kv.x + q2.y*kv.y + q2.z*kv.z + q2.w*kv.w;
            a3 += q3.x*kv.x + q3.y*kv.y + q3.z*kv.z + q3.w*kv.w;
            a4 += q4.x*kv.x + q4.y*kv.y + q4.z*kv.z + q4.w*kv.w;
        }
        float kbj = krow[128];
        float scs[5] = {a0+kbj, a1+kbj, a2+kbj, a3+kbj, a4+kbj};
        #pragma unroll
        for (int i = 0; i < 5; ++i) {
            float cv = scs[i]; int ci = i*Sz + j;        // flat idx = i*S + j (ref order)
            #pragma unroll
            for (int k = 0; k < 10; ++k) {
                bool bet = (cv > sv[k]) || (cv == sv[k] && ci < si[k]);
                float tvv = sv[k]; int tii = si[k];
                if (bet) { sv[k] = cv; si[k] = ci; cv = tvv; ci = tii; }
            }
        }
    }

    // 10 rounds of global max (desc value, tie -> lower index), matching lax.top_k order
    float vmax = 0.f, myv = 0.f; int myidx = 0x7FFFFFFF;
    #pragma unroll
    for (int rnd = 0; rnd < 10; ++rnd) {
        float v = sv[0]; int idx = si[0];
        #pragma unroll
        for (int off = 32; off >= 1; off >>= 1) {
            float ov = __shfl_xor(v, off);
            int   oi = __shfl_xor(idx, off);
            if (ov > v || (ov == v && oi < idx)) { v = ov; idx = oi; }
        }
        if (rnd == 0) vmax = v;
        if (lane == rnd) { myv = v; myidx = idx; }
        if (si[0] == idx) {   // owner pops its head
            #pragma unroll
            for (int k = 0; k < 9; ++k) { sv[k] = sv[k+1]; si[k] = si[k+1]; }
            sv[9] = NEG; si[9] = 0x7FFFFFFF;
        }
    }

    float num = 0.f, den = 0.f;
    if (lane < 10 && myidx != 0x7FFFFFFF) {
        float a = expf(myv - vmax);
        int ik = myidx / Sz, jk = myidx % Sz;
        float gsj = kqb[(size_t)(b*Tz + jk)*132 + 129];       // Ww-state dot + bw
        float f = 1.f/(1.f + expf(-(gq[ik] + gsj)));
        num = a*f; den = a;
    }
    #pragma unroll
    for (int off = 32; off >= 1; off >>= 1) {
        num += __shfl_xor(num, off);
        den += __shfl_xor(den, off);
    }
    if (lane == 0) out[b*Sz + t + 1] = num/den;
}

// ---------------- host ----------------
static inline size_t alup(size_t x) { return (x + 255) & ~(size_t)255; }

extern "C" void kernel_launch(void* const* d_in, const int* in_sizes, int n_in,
                              void* d_out, int out_size, void* d_ws, size_t ws_size,
                              hipStream_t stream) {
    (void)in_sizes; (void)n_in; (void)ws_size;
    const float* emb_q = (const float*)d_in[0];
    const float* emb_c = (const float*)d_in[1];
    const float* emb_r = (const float*)d_in[2];
    const float* Wih1  = (const float*)d_in[3];
    const float* Whh1  = (const float*)d_in[4];
    const float* bih1  = (const float*)d_in[5];
    const float* bhh1  = (const float*)d_in[6];
    const float* Wih2  = (const float*)d_in[7];
    const float* Whh2  = (const float*)d_in[8];
    const float* bih2  = (const float*)d_in[9];
    const float* bhh2  = (const float*)d_in[10];
    const float* Wg1   = (const float*)d_in[11];
    const float* Wg2   = (const float*)d_in[12];
    const float* Wg3   = (const float*)d_in[13];
    const float* Wagg  = (const float*)d_in[14];
    const float* bagg  = (const float*)d_in[15];
    const float* Wq    = (const float*)d_in[16];
    const float* bq    = (const float*)d_in[17];
    const float* Wk    = (const float*)d_in[18];
    const float* bk    = (const float*)d_in[19];
    const float* Ww    = (const float*)d_in[20];
    const float* bw    = (const float*)d_in[21];
    const int* qseq    = (const int*)d_in[22];
    const int* cseq    = (const int*)d_in[23];
    const int* mseq    = (const int*)d_in[24];
    const int* qtab    = (const int*)d_in[25];
    float* out = (float*)d_out;

    char* p = (char*)d_ws;
    auto alloc = [&](size_t bytes) { char* r = p; p += alup(bytes); return r; };
    int*   cnt    = (int*)  alloc(4096);
    int*   fill   = (int*)  alloc(4096);               // contiguous with cnt
    int*   offs   = (int*)  alloc(1001*4);
    int*   edge_q = (int*)  alloc((size_t)NEz*4);
    float* m2     = (float*)alloc((size_t)NCz*128*4);
    float* T1     = (float*)alloc(128*128*4);
    float* T2     = (float*)alloc(128*128*4);
    float* Mt     = (float*)alloc(128*128*4);
    float* gr     = (float*)alloc(2*384*4);
    float* Bkq    = (float*)alloc(132*128*4);
    float* biaskq = (float*)alloc(132*4);
    float* eq     = (float*)alloc((size_t)NSz*128*4);
    float* gi1    = (float*)alloc((size_t)NSz*384*4);
    float* stateh = (float*)alloc((size_t)NSz*128*4);
    float* kqb    = (float*)alloc((size_t)NSz*132*4);
    // aliases: eq is dead after the gi1 GEMM -> reuse as h1 sequence;
    //          gi1 is dead after scan1 -> reuse as gi2.
    float* h1all = eq;
    float* gi2   = gi1;

    hipMemsetAsync(cnt, 0, 8192, stream);                       // cnt + fill
    hipMemsetAsync(d_out, 0, (size_t)out_size*4, stream);       // y[:,0] = 0

    k_count<<<(NEz+255)/256, 256, 0, stream>>>(qtab, cnt);
    k_offs <<<1, 1024, 0, stream>>>(cnt, offs);
    k_fill <<<(NEz+255)/256, 256, 0, stream>>>(qtab, offs, fill, edge_q);
    k_m2   <<<NCz, 512, 0, stream>>>(qtab, offs, edge_q, emb_q, emb_c, m2);

    k_mm128<false><<<128, 128, 0, stream>>>(Wg2, Wg1, T1);      // T1 = Wg2*Wg1
    k_mm128<false><<<128, 128, 0, stream>>>(Wg3, T1, T2);       // T2 = Wg3*T1
    k_mm128<true> <<<128, 128, 0, stream>>>(Wagg, T2, Mt);      // Mt = (Wagg*T2)^T
    k_gr  <<<1, 768, 0, stream>>>(emb_r, Wih1, bih1, gr);
    k_bkq <<<130, 128, 0, stream>>>(Wq, Wk, bq, bk, Ww, bw, Bkq, biaskq);

    k_eq  <<<NSz/16, 256, 0, stream>>>(Mt, bagg, emb_q, emb_c, m2, qseq, mseq, qtab, eq);

    // gi1 = eq @ Wih1[:, :128]^T + gr[r_t]   (input gates, layer 1)
    k_gemm<1><<<dim3(NSz/64, 6), dim3(16,16), 0, stream>>>(eq, Wih1, 256, 384,
                                                           gi1, 384, nullptr, gr, cseq);
    // layer-1 scan (Whh1 only) -> h1 sequence (overwrites eq)
    k_scan<<<Bz, 768, 0, stream>>>(gi1, Whh1, bhh1, h1all);
    // gi2 = h1 @ Wih2^T + bih2  (input gates, layer 2; overwrites gi1)
    k_gemm<0><<<dim3(NSz/64, 6), dim3(16,16), 0, stream>>>(h1all, Wih2, 128, 384,
                                                           gi2, 384, bih2, nullptr, nullptr);
    // layer-2 scan (Whh2 only) -> h2 sequence
    k_scan<<<Bz, 768, 0, stream>>>(gi2, Whh2, bhh2, stateh);

    k_gemm<0><<<dim3(NSz/64, 3), dim3(16,16), 0, stream>>>(stateh, Bkq, 128, 132,
                                                           kqb, 132, biaskq, nullptr, nullptr);
    k_attn<<<dim3(Tz, Bz), 64, 0, stream>>>(kqb, qseq, qtab, emb_q, emb_c, Ww, out);
}

// Round 7
// 659.593 us; speedup vs baseline: 1.9693x; 1.1616x over previous
//
#include <hip/hip_runtime.h>
#include <math.h>

#define Bz 64
#define Sz 200
#define Dz 128
#define NQz 50000
#define NCz 1000
#define MCz 4
#define Kz 10
#define Tz 199            // S-1 scan steps
#define NSz (Bz*Tz)       // 12736 (b,t) slots; 12736/64 = 199 exactly
#define NEz (NQz*MCz)     // 200000 edges

// ---------------- GNN: CSR build + per-concept aggregation ----------------
__global__ void k_count(const int* __restrict__ qt, int* __restrict__ cnt) {
    int e = blockIdx.x*256 + threadIdx.x;
    if (e < NEz) atomicAdd(&cnt[qt[e]], 1);
}

__global__ void k_offs(const int* __restrict__ cnt, int* __restrict__ offs) {
    __shared__ int s[1024];
    int tid = threadIdx.x;
    s[tid] = (tid < NCz) ? cnt[tid] : 0;
    __syncthreads();
    for (int off = 1; off < 1024; off <<= 1) {
        int add = (tid >= off) ? s[tid - off] : 0;
        __syncthreads();
        s[tid] += add;
        __syncthreads();
    }
    if (tid < NCz) offs[tid + 1] = s[tid];
    if (tid == 0) offs[0] = 0;
}

__global__ void k_fill(const int* __restrict__ qt, const int* __restrict__ offs,
                       int* __restrict__ fill, int* __restrict__ edge_q) {
    int e = blockIdx.x*256 + threadIdx.x;
    if (e < NEz) {
        int c = qt[e];
        int pos = atomicAdd(&fill[c], 1);
        edge_q[offs[c] + pos] = e >> 2;     // question id
    }
}

// m2[c] = mean over edges (q->c) of ( emb_q[q] + 0.25*sum_m emb_c[q_table[q][m]] )
__global__ void k_m2(const int* __restrict__ qt, const int* __restrict__ offs,
                     const int* __restrict__ edge_q,
                     const float* __restrict__ emb_q, const float* __restrict__ emb_c,
                     float* __restrict__ m2) {
    int c = blockIdx.x;
    int g = threadIdx.x >> 7;      // 0..3
    int d = threadIdx.x & 127;
    int e0 = offs[c], e1 = offs[c+1];
    float acc = 0.f;
    for (int e = e0 + g; e < e1; e += 4) {
        int q = edge_q[e];
        const int* t4 = qt + q*4;
        int c0 = t4[0], c1 = t4[1], c2 = t4[2], c3 = t4[3];
        acc += emb_q[q*128 + d]
             + 0.25f*(emb_c[c0*128+d] + emb_c[c1*128+d] + emb_c[c2*128+d] + emb_c[c3*128+d]);
    }
    __shared__ float ps[4][128];
    ps[g][d] = acc;
    __syncthreads();
    if (g == 0) {
        float tot = ps[0][d] + ps[1][d] + ps[2][d] + ps[3][d];
        float cn = (float)(e1 - e0);
        m2[c*128 + d] = tot / fmaxf(cn, 1.0f);
    }
}

// ---------------- small 128x128 matmuls (weight folding) ----------------
template<bool TR>
__global__ void k_mm128(const float* __restrict__ X, const float* __restrict__ Y,
                        float* __restrict__ out) {
    int r = blockIdx.x, c = threadIdx.x;
    float acc = 0.f;
    for (int e = 0; e < 128; ++e) acc += X[r*128 + e] * Y[e*128 + c];
    if (TR) out[c*128 + r] = acc;           // store transposed (Mt[d][r] = M[r][d])
    else    out[r*128 + c] = acc;
}

// gr[rt][r] = bih1[r] + sum_e emb_r[rt][e]*Wih1[r][128+e]   (response-part of gi1, bias folded)
__global__ void k_gr(const float* __restrict__ emb_r, const float* __restrict__ Wih1,
                     const float* __restrict__ bih1, float* __restrict__ gr) {
    int rt = threadIdx.x / 384, r = threadIdx.x % 384;   // block 768
    float acc = bih1[r];
    for (int e = 0; e < 128; ++e) acc += emb_r[rt*128 + e] * Wih1[r*256 + 128 + e];
    gr[rt*384 + r] = acc;
}

// Bkq rows 0..127: G = Wq^T Wk;  row 128: wkb = Wk^T bq;  row 129: Ww[0][128:256]
// biaskq: 0..127: Wq^T bk;  128: bq.bk;  129: bw
__global__ void k_bkq(const float* __restrict__ Wq, const float* __restrict__ Wk,
                      const float* __restrict__ bq, const float* __restrict__ bk,
                      const float* __restrict__ Ww, const float* __restrict__ bw,
                      float* __restrict__ Bkq, float* __restrict__ biaskq) {
    int r = blockIdx.x, d = threadIdx.x;
    if (r < 128) {
        float acc = 0.f;
        for (int n = 0; n < 128; ++n) acc += Wq[n*128 + r] * Wk[n*128 + d];
        Bkq[r*128 + d] = acc;
        if (d == 0) {
            float b0 = 0.f;
            for (int n = 0; n < 128; ++n) b0 += Wq[n*128 + r] * bk[n];
            biaskq[r] = b0;
        }
    } else if (r == 128) {
        float acc = 0.f;
        for (int n = 0; n < 128; ++n) acc += bq[n] * Wk[n*128 + d];
        Bkq[128*128 + d] = acc;
        if (d == 0) {
            float c0 = 0.f;
            for (int n = 0; n < 128; ++n) c0 += bq[n] * bk[n];
            biaskq[128] = c0;
        }
    } else {
        Bkq[129*128 + d] = Ww[128 + d];
        if (d == 0) biaskq[129] = bw[0];
    }
}

// ---------------- per-slot GNN question embedding ----------------
// e_q[slot] = mask ? tanh(u @ M^T + bagg) : emb_q[q],  u = emb_q + 0.5*sum(emb_c) + 0.25*sum(m2)
__global__ void k_eq(const float* __restrict__ Mt_g, const float* __restrict__ bagg,
                     const float* __restrict__ emb_q, const float* __restrict__ emb_c,
                     const float* __restrict__ m2, const int* __restrict__ qseq,
                     const int* __restrict__ mseq, const int* __restrict__ qt,
                     float* __restrict__ eq) {
    __shared__ float Mt[128*128];
    __shared__ float ub[2][128];
    int tid = threadIdx.x;
    for (int i = tid; i < 128*128/4; i += 256)
        ((float4*)Mt)[i] = ((const float4*)Mt_g)[i];
    __syncthreads();
    int g = tid >> 7, d = tid & 127;
    for (int it = 0; it < 8; ++it) {
        int slot = blockIdx.x*16 + it*2 + g;            // grid 796 -> slots exactly cover NSz
        int b = slot / Tz, t = slot % Tz;
        int q = qseq[b*Sz + t];
        int msk = mseq[b*Sz + t];
        if (msk) {
            const int* t4 = qt + q*4;
            int c0 = t4[0], c1 = t4[1], c2 = t4[2], c3 = t4[3];
            ub[g][d] = emb_q[q*128 + d]
                     + 0.5f *(emb_c[c0*128+d] + emb_c[c1*128+d] + emb_c[c2*128+d] + emb_c[c3*128+d])
                     + 0.25f*(m2[c0*128+d]  + m2[c1*128+d]  + m2[c2*128+d]  + m2[c3*128+d]);
        }
        __syncthreads();
        if (msk) {
            float acc = bagg[d];
            const float* urow = ub[g];
            for (int e = 0; e < 128; ++e) acc += Mt[e*128 + d] * urow[e];
            eq[slot*128 + d] = tanhf(acc);
        } else {
            eq[slot*128 + d] = emb_q[q*128 + d];
        }
        __syncthreads();
    }
}

// ---------------- numeric helpers ----------------
__device__ __forceinline__ float bf_lo(unsigned u){ return __uint_as_float(u << 16); }
__device__ __forceinline__ float bf_hi(unsigned u){ return __uint_as_float(u & 0xffff0000u); }
__device__ __forceinline__ unsigned f2bf(float x){          // RNE round to bf16 (bits in low 16)
    unsigned u = __float_as_uint(x);
    return (u + 0x7fffu + ((u >> 16) & 1u)) >> 16;
}
__device__ __forceinline__ unsigned pk2(float a, float b){
    return f2bf(a) | (f2bf(b) << 16);
}
__device__ __forceinline__ float rcpf(float x){ return __builtin_amdgcn_rcpf(x); }
__device__ __forceinline__ float sigm(float x){ return rcpf(1.f + __expf(-x)); }
__device__ __forceinline__ float tanh_fast(float x){
    float e = __expf(2.f*x);
    return 1.f - 2.f*rcpf(e + 1.f);
}

#if __has_builtin(__builtin_amdgcn_fdot2_f32_bf16)
typedef __attribute__((ext_vector_type(2))) short short2v;
__device__ __forceinline__ float bdot2(unsigned w, unsigned h, float acc) {
    return __builtin_amdgcn_fdot2_f32_bf16(__builtin_bit_cast(short2v, w),
                                           __builtin_bit_cast(short2v, h), acc, false);
}
#else
__device__ __forceinline__ float bdot2(unsigned w, unsigned h, float acc) {
    return acc + bf_lo(w)*bf_lo(h) + bf_hi(w)*bf_hi(h);
}
#endif

// ---------------- tiled GEMM: C[s][n] = A[s][:128] . Bm[n][:128] + epilogue ----------------
// MODE 0: + bias[n]   (kq / gi2 paths)     MODE 1: + gr[rt(s)][n]  (gi1 path)
// DOT2 1: stage LDS tiles as packed bf16 pairs, inner loop = v_dot2 (2 MAC/instr, half the
//         LDS reads). Used for gi GEMMs (error squashed by gate sigmoids). kqb stays fp32.
template<int MODE, int DOT2>
__global__ void k_gemm(const float* __restrict__ A, const float* __restrict__ Bm,
                       int ldb, int nB, float* __restrict__ C, int ldc,
                       const float* __restrict__ bias, const float* __restrict__ gr,
                       const int* __restrict__ cseq) {
    __shared__ int rtb[64];
    int tx = threadIdx.x, ty = threadIdx.y;
    int tid = ty*16 + tx;
    int m0 = blockIdx.x * 64;
    int n0 = blockIdx.y * 64;
    if (MODE == 1 && tid < 64) {
        int s = m0 + tid;
        int b = s / Tz, t = s % Tz;
        rtb[tid] = cseq[b*Sz + t];
    }
    float acc[4][4];
    #pragma unroll
    for (int i = 0; i < 4; ++i)
        #pragma unroll
        for (int j = 0; j < 4; ++j) acc[i][j] = 0.f;

    if (DOT2) {
        __shared__ unsigned As[64][17];     // 16 bf16-pairs per row (+1 pad)
        __shared__ unsigned Bs[64][17];
        for (int kc = 0; kc < 128; kc += 32) {
            #pragma unroll
            for (int l = 0; l < 2; ++l) {
                int v = tid*2 + l;                 // 0..511
                int row = v >> 3, c4 = (v & 7) << 2;
                int p0 = (kc + c4) >> 1 & 15;      // pair index within tile (0..14 even)
                float4 av = *(const float4*)(A + (size_t)(m0+row)*128 + kc + c4);
                As[row][p0]   = pk2(av.x, av.y);
                As[row][p0+1] = pk2(av.z, av.w);
                int nrow = n0 + row;
                float4 bv = make_float4(0.f, 0.f, 0.f, 0.f);
                if (nrow < nB) bv = *(const float4*)(Bm + (size_t)nrow*ldb + kc + c4);
                Bs[row][p0]   = pk2(bv.x, bv.y);
                Bs[row][p0+1] = pk2(bv.z, bv.w);
            }
            __syncthreads();
            #pragma unroll 4
            for (int kp = 0; kp < 16; ++kp) {
                unsigned av[4], bv[4];
                #pragma unroll
                for (int i = 0; i < 4; ++i) av[i] = As[ty*4+i][kp];
                #pragma unroll
                for (int j = 0; j < 4; ++j) bv[j] = Bs[tx*4+j][kp];
                #pragma unroll
                for (int i = 0; i < 4; ++i)
                    #pragma unroll
                    for (int j = 0; j < 4; ++j) acc[i][j] = bdot2(av[i], bv[j], acc[i][j]);
            }
            __syncthreads();
        }
    } else {
        __shared__ float Asf[64][33];
        __shared__ float Bsf[64][33];
        for (int kc = 0; kc < 128; kc += 32) {
            #pragma unroll
            for (int l = 0; l < 2; ++l) {
                int v = tid*2 + l;                 // 0..511
                int row = v >> 3, c4 = (v & 7) << 2;
                float4 av = *(const float4*)(A + (size_t)(m0+row)*128 + kc + c4);
                Asf[row][c4+0] = av.x; Asf[row][c4+1] = av.y; Asf[row][c4+2] = av.z; Asf[row][c4+3] = av.w;
                int nrow = n0 + row;
                float4 bv = make_float4(0.f, 0.f, 0.f, 0.f);
                if (nrow < nB) bv = *(const float4*)(Bm + (size_t)nrow*ldb + kc + c4);
                Bsf[row][c4+0] = bv.x; Bsf[row][c4+1] = bv.y; Bsf[row][c4+2] = bv.z; Bsf[row][c4+3] = bv.w;
            }
            __syncthreads();
            #pragma unroll 8
            for (int k = 0; k < 32; ++k) {
                float av[4], bv[4];
                #pragma unroll
                for (int i = 0; i < 4; ++i) av[i] = Asf[ty*4+i][k];
                #pragma unroll
                for (int j = 0; j < 4; ++j) bv[j] = Bsf[tx*4+j][k];
                #pragma unroll
                for (int i = 0; i < 4; ++i)
                    #pragma unroll
                    for (int j = 0; j < 4; ++j) acc[i][j] += av[i]*bv[j];
            }
            __syncthreads();
        }
    }
    #pragma unroll
    for (int i = 0; i < 4; ++i) {
        int s = m0 + ty*4 + i;
        #pragma unroll
        for (int j = 0; j < 4; ++j) {
            int col = n0 + tx*4 + j;
            if (col < nB) {
                float v = acc[i][j];
                if (MODE == 0) v += bias[col];
                else           v += gr[rtb[ty*4+i]*384 + col];
                C[(size_t)s*ldc + col] = v;
            }
        }
    }
}

// ---------------- single-layer GRU scan ----------------
// One block per batch row, 384 threads (6 waves). Thread r holds the FULL bf16 row of Whh
// (64 packed regs; ~95 VGPR total — under the 128-reg cap the backend picks for 384-thr
// blocks, so no spill). gh computed directly (no partial-sum pass); gates on 64 threads
// with fast rcp/exp transcendentals.
__global__ void __launch_bounds__(384, 1)
k_scan(const float* __restrict__ gi, const float* __restrict__ Whh,
       const float* __restrict__ bhh, float* __restrict__ hout) {
    int b = blockIdx.x, tid = threadIdx.x;

    unsigned w[64];
    {
        const float4* w4 = (const float4*)(Whh + (size_t)tid*128);
        #pragma unroll
        for (int k = 0; k < 32; ++k) {
            float4 v = w4[k];
            w[2*k] = pk2(v.x, v.y); w[2*k+1] = pk2(v.z, v.w);
        }
    }
    float bb = bhh[tid];

    __shared__ unsigned hb[64];        // h packed bf16 (128 units)
    __shared__ float gh[384];
    if (tid < 64) hb[tid] = 0u;

    float g0=0.f,g1=0.f,g2=0.f,g3=0.f,g4=0.f,g5=0.f;
    if (tid < 64) {
        const float2* gp = (const float2*)(gi + (size_t)(b*Tz)*384);
        float2 x0 = gp[tid], x1 = gp[tid+64], x2 = gp[tid+128];
        g0=x0.x; g1=x0.y; g2=x1.x; g3=x1.y; g4=x2.x; g5=x2.y;
    }
    __syncthreads();

    const uint4* hv = (const uint4*)hb;

    for (int t = 0; t < Tz; ++t) {
        float n0=0.f,n1=0.f,n2=0.f,n3=0.f,n4=0.f,n5=0.f;
        if (tid < 64 && t + 1 < Tz) {                 // prefetch next step's input gates
            const float2* gp = (const float2*)(gi + (size_t)(b*Tz + t + 1)*384);
            float2 x0 = gp[tid], x1 = gp[tid+64], x2 = gp[tid+128];
            n0=x0.x; n1=x0.y; n2=x1.x; n3=x1.y; n4=x2.x; n5=x2.y;
        }
        // full-row dot: 8 uniform ds_read_b128 + 64 dot2, 4 accumulators
        float a0=0.f, a1=0.f, a2=0.f, a3=0.f;
        #pragma unroll
        for (int k = 0; k < 8; ++k) {
            uint4 hp = hv[k];
            a0 = bdot2(w[4*k+0], hp.x, a0);
            a1 = bdot2(w[4*k+1], hp.y, a1);
            a2 = bdot2(w[4*k+2], hp.z, a2);
            a3 = bdot2(w[4*k+3], hp.w, a3);
        }
        gh[tid] = bb + ((a0+a1)+(a2+a3));
        __syncthreads();
        if (tid < 64) {   // gate phase: 2 units per thread
            int u = 2*tid;
            unsigned hp = hb[tid];
            float r0 = sigm(g0 + gh[u]);
            float r1 = sigm(g1 + gh[u+1]);
            float z0 = sigm(g2 + gh[u+128]);
            float z1 = sigm(g3 + gh[u+129]);
            float q0 = tanh_fast(g4 + r0*gh[u+256]);
            float q1 = tanh_fast(g5 + r1*gh[u+257]);
            float h0  = (1.f - z0)*q0 + z0*bf_lo(hp);
            float h1v = (1.f - z1)*q1 + z1*bf_hi(hp);
            hb[tid] = pk2(h0, h1v);
            ((float2*)(hout + (size_t)(b*Tz + t)*128))[tid] = make_float2(h0, h1v);
        }
        g0=n0; g1=n1; g2=n2; g3=n3; g4=n4; g5=n5;
        __syncthreads();
    }
}

// ---------------- attention + top-k + output, one wave per (b,t) ----------------
__global__ void k_attn(const float* __restrict__ kqb, const int* __restrict__ qseq,
                       const int* __restrict__ qt, const float* __restrict__ emb_q,
                       const float* __restrict__ emb_c, const float* __restrict__ Ww,
                       float* __restrict__ out) {
    int t = blockIdx.x, b = blockIdx.y;
    int lane = threadIdx.x;           // block = 64 = 1 wave
    __shared__ float qc[5][128];
    __shared__ float gq[5];
    int qn = qseq[b*Sz + t + 1];
    for (int idx = lane; idx < 5*128; idx += 64) {
        int i = idx >> 7, d = idx & 127;
        const float* src = (i == 0) ? (emb_q + (size_t)qn*128)
                                    : (emb_c + (size_t)qt[qn*4 + (i-1)]*128);
        qc[i][d] = src[d];
    }
    __syncthreads();
    if (lane < 5) {
        float acc = 0.f;
        for (int d = 0; d < 128; ++d) acc += qc[lane][d]*Ww[d];
        gq[lane] = acc;
    }
    __syncthreads();

    const float NEG = -3.402823466e38f;
    float sv[10]; int si[10];
    #pragma unroll
    for (int k = 0; k < 10; ++k) { sv[k] = NEG; si[k] = 0x7FFFFFFF; }

    for (int j = lane; j <= t; j += 64) {
        const float* krow = kqb + (size_t)(b*Tz + j)*132;
        const float4* kr4 = (const float4*)krow;
        float a0=0.f, a1=0.f, a2=0.f, a3=0.f, a4=0.f;
        #pragma unroll 4
        for (int c = 0; c < 32; ++c) {
            float4 kv = kr4[c];
            float4 q0 = ((const float4*)qc[0])[c];
            float4 q1 = ((const float4*)qc[1])[c];
            float4 q2 = ((const float4*)qc[2])[c];
            float4 q3 = ((const float4*)qc[3])[c];
            float4 q4 = ((const float4*)qc[4])[c];
            a0 += q0.x*kv.x + q0.y*kv.y + q0.z*kv.z + q0.w*kv.w;
            a1 += q1.x*kv.x + q1.y*kv.y + q1.z*kv.z + q1.w*kv.w;
            a2 += q2.x*kv.x + q2.y*kv.y + q2.z*kv.z + q2.w*kv.w;
            a3 += q3.x*kv.x + q3.y*kv.y + q3.z*kv.z + q3.w*kv.w;
            a4 += q4.x*kv.x + q4.y*kv.y + q4.z*kv.z + q4.w*kv.w;
        }
        float kbj = krow[128];
        float scs[5] = {a0+kbj, a1+kbj, a2+kbj, a3+kbj, a4+kbj};
        #pragma unroll
        for (int i = 0; i < 5; ++i) {
            float cv = scs[i]; int ci = i*Sz + j;        // flat idx = i*S + j (ref order)
            #pragma unroll
            for (int k = 0; k < 10; ++k) {
                bool bet = (cv > sv[k]) || (cv == sv[k] && ci < si[k]);
                float tvv = sv[k]; int tii = si[k];
                if (bet) { sv[k] = cv; si[k] = ci; cv = tvv; ci = tii; }
            }
        }
    }

    // 10 rounds of global max (desc value, tie -> lower index), matching lax.top_k order
    float vmax = 0.f, myv = 0.f; int myidx = 0x7FFFFFFF;
    #pragma unroll
    for (int rnd = 0; rnd < 10; ++rnd) {
        float v = sv[0]; int idx = si[0];
        #pragma unroll
        for (int off = 32; off >= 1; off >>= 1) {
            float ov = __shfl_xor(v, off);
            int   oi = __shfl_xor(idx, off);
            if (ov > v || (ov == v && oi < idx)) { v = ov; idx = oi; }
        }
        if (rnd == 0) vmax = v;
        if (lane == rnd) { myv = v; myidx = idx; }
        if (si[0] == idx) {   // owner pops its head
            #pragma unroll
            for (int k = 0; k < 9; ++k) { sv[k] = sv[k+1]; si[k] = si[k+1]; }
            sv[9] = NEG; si[9] = 0x7FFFFFFF;
        }
    }

    float num = 0.f, den = 0.f;
    if (lane < 10 && myidx != 0x7FFFFFFF) {
        float a = __expf(myv - vmax);
        int ik = myidx / Sz, jk = myidx % Sz;
        float gsj = kqb[(size_t)(b*Tz + jk)*132 + 129];       // Ww-state dot + bw
        float f = sigm(gq[ik] + gsj);
        num = a*f; den = a;
    }
    #pragma unroll
    for (int off = 32; off >= 1; off >>= 1) {
        num += __shfl_xor(num, off);
        den += __shfl_xor(den, off);
    }
    if (lane == 0) out[b*Sz + t + 1] = num/den;
}

// ---------------- host ----------------
static inline size_t alup(size_t x) { return (x + 255) & ~(size_t)255; }

extern "C" void kernel_launch(void* const* d_in, const int* in_sizes, int n_in,
                              void* d_out, int out_size, void* d_ws, size_t ws_size,
                              hipStream_t stream) {
    (void)in_sizes; (void)n_in; (void)ws_size;
    const float* emb_q = (const float*)d_in[0];
    const float* emb_c = (const float*)d_in[1];
    const float* emb_r = (const float*)d_in[2];
    const float* Wih1  = (const float*)d_in[3];
    const float* Whh1  = (const float*)d_in[4];
    const float* bih1  = (const float*)d_in[5];
    const float* bhh1  = (const float*)d_in[6];
    const float* Wih2  = (const float*)d_in[7];
    const float* Whh2  = (const float*)d_in[8];
    const float* bih2  = (const float*)d_in[9];
    const float* bhh2  = (const float*)d_in[10];
    const float* Wg1   = (const float*)d_in[11];
    const float* Wg2   = (const float*)d_in[12];
    const float* Wg3   = (const float*)d_in[13];
    const float* Wagg  = (const float*)d_in[14];
    const float* bagg  = (const float*)d_in[15];
    const float* Wq    = (const float*)d_in[16];
    const float* bq    = (const float*)d_in[17];
    const float* Wk    = (const float*)d_in[18];
    const float* bk    = (const float*)d_in[19];
    const float* Ww    = (const float*)d_in[20];
    const float* bw    = (const float*)d_in[21];
    const int* qseq    = (const int*)d_in[22];
    const int* cseq    = (const int*)d_in[23];
    const int* mseq    = (const int*)d_in[24];
    const int* qtab    = (const int*)d_in[25];
    float* out = (float*)d_out;

    char* p = (char*)d_ws;
    auto alloc = [&](size_t bytes) { char* r = p; p += alup(bytes); return r; };
    int*   cnt    = (int*)  alloc(4096);
    int*   fill   = (int*)  alloc(4096);               // contiguous with cnt
    int*   offs   = (int*)  alloc(1001*4);
    int*   edge_q = (int*)  alloc((size_t)NEz*4);
    float* m2     = (float*)alloc((size_t)NCz*128*4);
    float* T1     = (float*)alloc(128*128*4);
    float* T2     = (float*)alloc(128*128*4);
    float* Mt     = (float*)alloc(128*128*4);
    float* gr     = (float*)alloc(2*384*4);
    float* Bkq    = (float*)alloc(132*128*4);
    float* biaskq = (float*)alloc(132*4);
    float* eq     = (float*)alloc((size_t)NSz*128*4);
    float* gi1    = (float*)alloc((size_t)NSz*384*4);
    float* stateh = (float*)alloc((size_t)NSz*128*4);
    float* kqb    = (float*)alloc((size_t)NSz*132*4);
    // aliases: eq is dead after the gi1 GEMM -> reuse as h1 sequence;
    //          gi1 is dead after scan1 -> reuse as gi2.
    float* h1all = eq;
    float* gi2   = gi1;

    hipMemsetAsync(cnt, 0, 8192, stream);                       // cnt + fill
    hipMemsetAsync(d_out, 0, (size_t)out_size*4, stream);       // y[:,0] = 0

    k_count<<<(NEz+255)/256, 256, 0, stream>>>(qtab, cnt);
    k_offs <<<1, 1024, 0, stream>>>(cnt, offs);
    k_fill <<<(NEz+255)/256, 256, 0, stream>>>(qtab, offs, fill, edge_q);
    k_m2   <<<NCz, 512, 0, stream>>>(qtab, offs, edge_q, emb_q, emb_c, m2);

    k_mm128<false><<<128, 128, 0, stream>>>(Wg2, Wg1, T1);      // T1 = Wg2*Wg1
    k_mm128<false><<<128, 128, 0, stream>>>(Wg3, T1, T2);       // T2 = Wg3*T1
    k_mm128<true> <<<128, 128, 0, stream>>>(Wagg, T2, Mt);      // Mt = (Wagg*T2)^T
    k_gr  <<<1, 768, 0, stream>>>(emb_r, Wih1, bih1, gr);
    k_bkq <<<130, 128, 0, stream>>>(Wq, Wk, bq, bk, Ww, bw, Bkq, biaskq);

    k_eq  <<<NSz/16, 256, 0, stream>>>(Mt, bagg, emb_q, emb_c, m2, qseq, mseq, qtab, eq);

    // gi1 = eq @ Wih1[:, :128]^T + gr[r_t]   (input gates, layer 1)  [bf16-dot2]
    k_gemm<1,1><<<dim3(NSz/64, 6), dim3(16,16), 0, stream>>>(eq, Wih1, 256, 384,
                                                             gi1, 384, nullptr, gr, cseq);
    // layer-1 scan (Whh1 only) -> h1 sequence (overwrites eq)
    k_scan<<<Bz, 384, 0, stream>>>(gi1, Whh1, bhh1, h1all);
    // gi2 = h1 @ Wih2^T + bih2  (input gates, layer 2; overwrites gi1)  [bf16-dot2]
    k_gemm<0,1><<<dim3(NSz/64, 6), dim3(16,16), 0, stream>>>(h1all, Wih2, 128, 384,
                                                             gi2, 384, bih2, nullptr, nullptr);
    // layer-2 scan (Whh2 only) -> h2 sequence
    k_scan<<<Bz, 384, 0, stream>>>(gi2, Whh2, bhh2, stateh);

    // kqb: fp32 path (attention scores / top-k ordering untouched)
    k_gemm<0,0><<<dim3(NSz/64, 3), dim3(16,16), 0, stream>>>(stateh, Bkq, 128, 132,
                                                             kqb, 132, biaskq, nullptr, nullptr);
    k_attn<<<dim3(Tz, Bz), 64, 0, stream>>>(kqb, qseq, qtab, emb_q, emb_c, Ww, out);
}